// Round 2
// baseline (384.237 us; speedup 1.0000x reference)
//
#include <hip/hip_runtime.h>
#include <hip/hip_bf16.h>
#include <stdint.h>

#define DEV __device__ __forceinline__

typedef __attribute__((ext_vector_type(4))) float f32x4;
typedef __attribute__((ext_vector_type(8))) __bf16 bf16x8;
typedef __attribute__((ext_vector_type(4))) __bf16 bf16x4;
typedef __attribute__((ext_vector_type(4))) unsigned int uint4v;

static constexpr int Bc = 4, Sc = 1024, DMc = 1024, Hc = 16, Dh = 64;
static constexpr int Mc = Bc * Sc; // 4096

DEV __bf16 f2b(float x) {
    unsigned u = __builtin_bit_cast(unsigned, x);
    unsigned r = (u + 0x7fffu + ((u >> 16) & 1u)) >> 16;
    return __builtin_bit_cast(__bf16, (unsigned short)r);
}
DEV float b2f(__bf16 x) {
    unsigned short s = __builtin_bit_cast(unsigned short, x);
    unsigned u = ((unsigned)s) << 16;
    return __builtin_bit_cast(float, u);
}

DEV void gload_lds16(const void* g, void* l) {
    __builtin_amdgcn_global_load_lds(
        (const __attribute__((address_space(1))) unsigned int*)g,
        (__attribute__((address_space(3))) unsigned int*)l,
        16, 0, 0);
}

// ---------------- convert f32 -> bf16 (elementwise) ----------------
__global__ void k_cvt(const float* __restrict__ in, __bf16* __restrict__ out, int n) {
    int i = (blockIdx.x * blockDim.x + threadIdx.x) * 4;
    if (i < n) {
        float4 v = *(const float4*)&in[i];
        bf16x4 o = { f2b(v.x), f2b(v.y), f2b(v.z), f2b(v.w) };
        *(bf16x4*)&out[i] = o;
    }
}

// ---------------- transpose-convert: out[c][r] = bf16(in[r][c]) ----------------
__global__ void k_tcvt(const float* __restrict__ in, __bf16* __restrict__ out, int R, int C) {
    __shared__ float t[32][33];
    int c0 = blockIdx.x * 32, r0 = blockIdx.y * 32;
    for (int j = 0; j < 4; j++)
        t[threadIdx.y + j * 8][threadIdx.x] = in[(size_t)(r0 + threadIdx.y + j * 8) * C + c0 + threadIdx.x];
    __syncthreads();
    for (int j = 0; j < 4; j++)
        out[(size_t)(c0 + threadIdx.y + j * 8) * R + r0 + threadIdx.x] = f2b(t[threadIdx.x][threadIdx.y + j * 8]);
}

// ---------------- GEMM: C[M][N] = A[M][K] @ W[K][N] + bias ----------------
// A bf16 [M][K], Bt bf16 [N][K] (W^T). EPI: 0=bf16 out, 1=bf16 tanh(x+bias2[row>>10][n]), 2=f32 out
template <int EPI>
__global__ __launch_bounds__(256) void k_gemm(
    const __bf16* __restrict__ A, const __bf16* __restrict__ Bt,
    const float* __restrict__ bias, const float* __restrict__ bias2,
    void* __restrict__ Cout, int N, int K)
{
    constexpr int BM = 128, BN = 128, BK = 32;
    __shared__ __bf16 Al[BM * BK];
    __shared__ __bf16 Bl[BN * BK];
    const int bm = blockIdx.x, bn = blockIdx.y;
    const int tid = threadIdx.x, lane = tid & 63, wid = tid >> 6;
    const int l15 = lane & 15, lg = lane >> 4;
    const int qr = (wid >> 1) * 64, qc = (wid & 1) * 64;
    f32x4 acc[4][4] = {};

    const __bf16* Ab = A + (size_t)(bm * BM) * K;
    const __bf16* Bb = Bt + (size_t)(bn * BN) * K;

    for (int k0 = 0; k0 < K; k0 += BK) {
        for (int c = 0; c < 2; c++) {
            int chunk = wid * 2 + c;
            int e = chunk * 512 + lane * 8;
            int row = e >> 5, col = e & 31;
            gload_lds16(Ab + (size_t)row * K + k0 + col, &Al[chunk * 512]);
            gload_lds16(Bb + (size_t)row * K + k0 + col, &Bl[chunk * 512]);
        }
        __syncthreads();
        bf16x8 af[4], bfv[4];
        for (int m = 0; m < 4; m++) af[m] = *(const bf16x8*)&Al[(qr + m * 16 + l15) * 32 + lg * 8];
        for (int n = 0; n < 4; n++) bfv[n] = *(const bf16x8*)&Bl[(qc + n * 16 + l15) * 32 + lg * 8];
        for (int m = 0; m < 4; m++)
            for (int n = 0; n < 4; n++)
                acc[m][n] = __builtin_amdgcn_mfma_f32_16x16x32_bf16(af[m], bfv[n], acc[m][n], 0, 0, 0);
        __syncthreads();
    }
    for (int m = 0; m < 4; m++) {
        int row_base = bm * BM + qr + m * 16 + lg * 4;
        for (int n = 0; n < 4; n++) {
            int col = bn * BN + qc + n * 16 + l15;
            float bsum = bias[col];
            for (int r = 0; r < 4; r++) {
                int row = row_base + r;
                float v = acc[m][n][r] + bsum;
                if constexpr (EPI == 1) v = tanhf(v + bias2[(row >> 10) * 1024 + col]);
                if constexpr (EPI == 2) ((float*)Cout)[(size_t)row * N + col] = v;
                else ((__bf16*)Cout)[(size_t)row * N + col] = f2b(v);
            }
        }
    }
}

// ---------------- glo[b][n] = mean_s mq[b,s,n] ----------------
__global__ void k_glo(const __bf16* __restrict__ mq, float* __restrict__ glo) {
    int i = blockIdx.x * blockDim.x + threadIdx.x; // 4096
    int b = i >> 10, n = i & 1023;
    const __bf16* p = mq + (size_t)b * Sc * DMc + n;
    float s = 0.f;
    for (int t = 0; t < Sc; t++) s += b2f(p[(size_t)t * DMc]);
    glo[i] = s * (1.0f / Sc);
}

// ---------------- gterm[b][n] = glo[b]@wfg[:,n] + bfg[n] (fp32) ----------------
__global__ void k_gterm(const float* __restrict__ glo, const float* __restrict__ wfg,
                        const float* __restrict__ bfg, float* __restrict__ gt) {
    int tid = threadIdx.x, lane = tid & 63, wid = tid >> 6;
    int o = blockIdx.x * 64 + wid * 16 + (lane & 15);
    int sl = lane >> 4;
    int b = o >> 10, n = o & 1023;
    float s = 0.f;
    for (int k = sl; k < DMc; k += 4) s += glo[(b << 10) + k] * wfg[(size_t)k * DMc + n];
    s += __shfl_xor(s, 16, 64);
    s += __shfl_xor(s, 32, 64);
    if (sl == 0) gt[o] = s + bfg[n];
}

// ---------------- P,Z from c ----------------
__global__ void k_pz(const __bf16* __restrict__ c, const float* __restrict__ up,
                     const float* __restrict__ uz, float* __restrict__ Pf, float* __restrict__ Zf) {
    int i = blockIdx.x * blockDim.x + threadIdx.x; // B*H*S = 65536
    int b = i >> 14, h = (i >> 10) & 15, s = i & 1023;
    const __bf16* cp = c + ((size_t)(b * Sc + s)) * DMc + h * Dh;
    float p = 0.f, z = 0.f;
    for (int d = 0; d < Dh; d++) {
        float cv = b2f(cp[d]);
        p += cv * up[h * Dh + d];
        z += cv * uz[h * Dh + d];
    }
    Pf[i] = 1024.f / (1.f + __expf(-p));
    Zf[i] = 1024.f / (1.f + __expf(-z));
}

// ---------------- flash attention with Gaussian focus bias ----------------
__global__ __launch_bounds__(256) void k_attn(
    const __bf16* __restrict__ Q, const __bf16* __restrict__ Kx, const __bf16* __restrict__ Vx,
    const float* __restrict__ Pf, const float* __restrict__ Zf, __bf16* __restrict__ ctx)
{
    __shared__ __bf16 Kl[32 * 64];
    __shared__ __bf16 Vt[64 * 32];
    __shared__ __bf16 Pl[4 * 16 * 32];
    const int qt = blockIdx.x, h = blockIdx.y, b = blockIdx.z;
    const int tid = threadIdx.x, lane = tid & 63, wid = tid >> 6;
    const int l15 = lane & 15, lg = lane >> 4;
    const int qbase = qt * 64 + wid * 16;
    const size_t headoff = ((size_t)b * Sc) * DMc + h * Dh;

    bf16x8 qf[2];
    for (int c = 0; c < 2; c++)
        qf[c] = *(const bf16x8*)&Q[headoff + (size_t)(qbase + l15) * DMc + c * 32 + lg * 8];

    float Pr[4], Ar[4];
    for (int r = 0; r < 4; r++) {
        int row = qbase + lg * 4 + r;
        float pp = Pf[((size_t)b * Hc + h) * Sc + row];
        float zz = Zf[((size_t)b * Hc + h) * Sc + row];
        Pr[r] = pp; Ar[r] = 2.0f / (zz * zz);
    }
    float mrow[4], lrow[4];
    f32x4 oacc[4] = {};
    for (int r = 0; r < 4; r++) { mrow[r] = -__builtin_inff(); lrow[r] = 0.f; }

    for (int kv = 0; kv < Sc; kv += 32) {
        {   // stage K [32][64] and V^T [64][32]
            int krow = tid >> 3, kcol = (tid & 7) * 8;
            uint4v k4 = *(const uint4v*)&Kx[headoff + (size_t)(kv + krow) * DMc + kcol];
            *(uint4v*)&Kl[krow * 64 + kcol] = k4;
            uint4v v4 = *(const uint4v*)&Vx[headoff + (size_t)(kv + krow) * DMc + kcol];
            bf16x8 vv = __builtin_bit_cast(bf16x8, v4);
            for (int j = 0; j < 8; j++) Vt[(kcol + j) * 32 + krow] = vv[j];
        }
        __syncthreads();

        f32x4 sc[2];
        for (int t = 0; t < 2; t++) {
            bf16x8 kb0 = *(const bf16x8*)&Kl[(t * 16 + l15) * 64 + lg * 8];
            bf16x8 kb1 = *(const bf16x8*)&Kl[(t * 16 + l15) * 64 + 32 + lg * 8];
            f32x4 z4 = {};
            z4 = __builtin_amdgcn_mfma_f32_16x16x32_bf16(qf[0], kb0, z4, 0, 0, 0);
            sc[t] = __builtin_amdgcn_mfma_f32_16x16x32_bf16(qf[1], kb1, z4, 0, 0, 0);
        }
        for (int r = 0; r < 4; r++) {
            float dk0 = (float)(kv + l15) - Pr[r];
            float dk1 = (float)(kv + 16 + l15) - Pr[r];
            float s0 = sc[0][r] * 0.125f - dk0 * dk0 * Ar[r];
            float s1 = sc[1][r] * 0.125f - dk1 * dk1 * Ar[r];
            float mx = fmaxf(s0, s1);
            for (int d = 1; d < 16; d <<= 1) mx = fmaxf(mx, __shfl_xor(mx, d, 64));
            float nm = fmaxf(mrow[r], mx);
            float scf = __expf(mrow[r] - nm);
            float p0 = __expf(s0 - nm), p1 = __expf(s1 - nm);
            float rs = p0 + p1;
            for (int d = 1; d < 16; d <<= 1) rs += __shfl_xor(rs, d, 64);
            lrow[r] = lrow[r] * scf + rs;
            mrow[r] = nm;
            for (int dt = 0; dt < 4; dt++) oacc[dt][r] *= scf;
            Pl[wid * 512 + (lg * 4 + r) * 32 + l15] = f2b(p0);
            Pl[wid * 512 + (lg * 4 + r) * 32 + 16 + l15] = f2b(p1);
        }
        __syncthreads();
        bf16x8 pa = *(const bf16x8*)&Pl[wid * 512 + l15 * 32 + lg * 8];
        for (int dt = 0; dt < 4; dt++) {
            bf16x8 vb = *(const bf16x8*)&Vt[(dt * 16 + l15) * 32 + lg * 8];
            oacc[dt] = __builtin_amdgcn_mfma_f32_16x16x32_bf16(pa, vb, oacc[dt], 0, 0, 0);
        }
        __syncthreads();
    }
    for (int dt = 0; dt < 4; dt++)
        for (int r = 0; r < 4; r++) {
            int row = qbase + lg * 4 + r;
            ctx[((size_t)b * Sc + row) * DMc + h * Dh + dt * 16 + l15] = f2b(oacc[dt][r] / lrow[r]);
        }
}

extern "C" void kernel_launch(void* const* d_in, const int* in_sizes, int n_in,
                              void* d_out, int out_size, void* d_ws, size_t ws_size,
                              hipStream_t stream) {
    const float* hs  = (const float*)d_in[0];
    const float* wq  = (const float*)d_in[1];
    const float* bq  = (const float*)d_in[2];
    const float* wk  = (const float*)d_in[3];
    const float* bk  = (const float*)d_in[4];
    const float* wv  = (const float*)d_in[5];
    const float* bv  = (const float*)d_in[6];
    const float* wo  = (const float*)d_in[7];
    const float* bo  = (const float*)d_in[8];
    const float* wfq = (const float*)d_in[9];
    const float* bfq = (const float*)d_in[10];
    const float* wfg = (const float*)d_in[11];
    const float* bfg = (const float*)d_in[12];
    const float* up  = (const float*)d_in[13];
    const float* uz  = (const float*)d_in[14];

    char* ws = (char*)d_ws;
    const size_t MB = 1ull << 20;
    __bf16* hsb  = (__bf16*)(ws);
    __bf16* wqT  = (__bf16*)(ws + 8 * MB);
    __bf16* wkT  = (__bf16*)(ws + 10 * MB);
    __bf16* wvT  = (__bf16*)(ws + 12 * MB);
    __bf16* wfqT = (__bf16*)(ws + 14 * MB);
    __bf16* woT  = (__bf16*)(ws + 16 * MB);
    __bf16* mq   = (__bf16*)(ws + 18 * MB);
    __bf16* mk   = (__bf16*)(ws + 26 * MB);
    __bf16* mv   = (__bf16*)(ws + 34 * MB);
    __bf16* cb   = (__bf16*)(ws + 42 * MB);
    __bf16* ctxb = (__bf16*)(ws + 50 * MB);
    float*  glo  = (float*)(ws + 58 * MB);
    float*  gt   = (float*)(ws + 58 * MB + (16 << 10));
    float*  Pf   = (float*)(ws + 58 * MB + (32 << 10));
    float*  Zf   = (float*)(ws + 58 * MB + (288 << 10));

    k_cvt<<<4096, 256, 0, stream>>>(hs, hsb, Mc * DMc);
    dim3 tb(32, 8);
    k_tcvt<<<dim3(32, 32), tb, 0, stream>>>(wq, wqT, DMc, DMc);
    k_tcvt<<<dim3(32, 32), tb, 0, stream>>>(wk, wkT, DMc, DMc);
    k_tcvt<<<dim3(32, 32), tb, 0, stream>>>(wv, wvT, DMc, DMc);
    k_tcvt<<<dim3(32, 32), tb, 0, stream>>>(wfq, wfqT, DMc, DMc);
    k_tcvt<<<dim3(32, 32), tb, 0, stream>>>(wo, woT, DMc, DMc);

    dim3 gg(32, 8);
    k_gemm<0><<<gg, 256, 0, stream>>>(hsb, wqT, bq, nullptr, mq, DMc, DMc);
    k_gemm<0><<<gg, 256, 0, stream>>>(hsb, wkT, bk, nullptr, mk, DMc, DMc);
    k_gemm<0><<<gg, 256, 0, stream>>>(hsb, wvT, bv, nullptr, mv, DMc, DMc);

    k_glo<<<16, 256, 0, stream>>>(mq, glo);
    k_gterm<<<64, 256, 0, stream>>>(glo, wfg, bfg, gt);
    k_gemm<1><<<gg, 256, 0, stream>>>(mq, wfqT, bfq, gt, cb, DMc, DMc);
    k_pz<<<256, 256, 0, stream>>>(cb, up, uz, Pf, Zf);

    k_attn<<<dim3(16, 16, 4), 256, 0, stream>>>(mq, mk, mv, Pf, Zf, ctxb);
    k_gemm<2><<<gg, 256, 0, stream>>>(ctxb, woT, bo, nullptr, d_out, DMc, DMc);
}

// Round 4
// 225.644 us; speedup vs baseline: 1.7028x; 1.7028x over previous
//
#include <hip/hip_runtime.h>
#include <hip/hip_bf16.h>
#include <stdint.h>

#define DEV __device__ __forceinline__

typedef __attribute__((ext_vector_type(4))) float f32x4;
typedef __attribute__((ext_vector_type(8))) __bf16 bf16x8;
typedef __attribute__((ext_vector_type(4))) __bf16 bf16x4;
typedef __attribute__((ext_vector_type(4))) unsigned int uint4v;
typedef __attribute__((ext_vector_type(4))) int i32x4;

static constexpr int Bc = 4, Sc = 1024, DMc = 1024, Hc = 16, Dh = 64;
static constexpr int Mc = Bc * Sc; // 4096

DEV __bf16 f2b(float x) {
    unsigned u = __builtin_bit_cast(unsigned, x);
    unsigned r = (u + 0x7fffu + ((u >> 16) & 1u)) >> 16;
    return __builtin_bit_cast(__bf16, (unsigned short)r);
}
DEV float b2f(__bf16 x) {
    unsigned short s = __builtin_bit_cast(unsigned short, x);
    unsigned u = ((unsigned)s) << 16;
    return __builtin_bit_cast(float, u);
}
DEV unsigned cvt_pk_bf16(float a, float b) {
    unsigned r;
    asm("v_cvt_pk_bf16_f32 %0, %1, %2" : "=v"(r) : "v"(a), "v"(b));
    return r;
}
DEV void gload_lds16(const void* g, void* l) {
    __builtin_amdgcn_global_load_lds(
        (const __attribute__((address_space(1))) unsigned int*)g,
        (__attribute__((address_space(3))) unsigned int*)l,
        16, 0, 0);
}

// ---------------- convert f32 -> bf16 ----------------
__global__ void k_cvt(const float* __restrict__ in, __bf16* __restrict__ out, int n) {
    int i = (blockIdx.x * blockDim.x + threadIdx.x) * 4;
    if (i < n) {
        float4 v = *(const float4*)&in[i];
        bf16x4 o = { f2b(v.x), f2b(v.y), f2b(v.z), f2b(v.w) };
        *(bf16x4*)&out[i] = o;
    }
}

// ---------------- transpose-convert: out[c][r] = bf16(in[r][c]) ----------------
__global__ void k_tcvt(const float* __restrict__ in, __bf16* __restrict__ out, int R, int C) {
    __shared__ float t[32][33];
    int c0 = blockIdx.x * 32, r0 = blockIdx.y * 32;
    for (int j = 0; j < 4; j++)
        t[threadIdx.y + j * 8][threadIdx.x] = in[(size_t)(r0 + threadIdx.y + j * 8) * C + c0 + threadIdx.x];
    __syncthreads();
    for (int j = 0; j < 4; j++)
        out[(size_t)(c0 + threadIdx.y + j * 8) * R + r0 + threadIdx.x] = f2b(t[threadIdx.x][threadIdx.y + j * 8]);
}

// ---------------- generic GEMM: C[M][N] = A@W + bias; Bt = W^T [N][K] ----------------
// EPI: 0 = bf16 out, 2 = f32 out. BM in {64,128}, BN=128, BK=32.
template <int EPI, int BM>
__global__ __launch_bounds__(256) void k_gemm(
    const __bf16* __restrict__ A, const __bf16* __restrict__ Bt,
    const float* __restrict__ bias, void* __restrict__ Cout, int N, int K)
{
    constexpr int MF = BM / 32;
    __shared__ __bf16 Al[BM * 32];
    __shared__ __bf16 Bl[128 * 32];
    const int bm = blockIdx.x, bn = blockIdx.y;
    const int tid = threadIdx.x, lane = tid & 63, wid = tid >> 6;
    const int l15 = lane & 15, lg = lane >> 4;
    const int qr = (wid >> 1) * (BM / 2), qc = (wid & 1) * 64;
    f32x4 acc[MF][4] = {};

    const __bf16* Ab = A + (size_t)bm * BM * K;
    const __bf16* Bb = Bt + (size_t)bn * 128 * K;

    for (int k0 = 0; k0 < K; k0 += 32) {
#pragma unroll
        for (int c = 0; c < BM / 64; c++) {
            int ch = c * 256 + tid;
            gload_lds16(&Ab[(size_t)(ch >> 2) * K + k0 + (ch & 3) * 8], &Al[ch * 8]);
        }
#pragma unroll
        for (int c = 0; c < 2; c++) {
            int ch = c * 256 + tid;
            gload_lds16(&Bb[(size_t)(ch >> 2) * K + k0 + (ch & 3) * 8], &Bl[ch * 8]);
        }
        __syncthreads();
        bf16x8 af[MF], bfv[4];
#pragma unroll
        for (int m = 0; m < MF; m++) af[m] = *(const bf16x8*)&Al[(qr + m * 16 + l15) * 32 + lg * 8];
#pragma unroll
        for (int n = 0; n < 4; n++) bfv[n] = *(const bf16x8*)&Bl[(qc + n * 16 + l15) * 32 + lg * 8];
#pragma unroll
        for (int m = 0; m < MF; m++)
#pragma unroll
            for (int n = 0; n < 4; n++)
                acc[m][n] = __builtin_amdgcn_mfma_f32_16x16x32_bf16(af[m], bfv[n], acc[m][n], 0, 0, 0);
        __syncthreads();
    }
#pragma unroll
    for (int m = 0; m < MF; m++) {
        int row_base = bm * BM + qr + m * 16 + lg * 4;
#pragma unroll
        for (int n = 0; n < 4; n++) {
            int col = bn * 128 + qc + n * 16 + l15;
            float bsum = bias ? bias[col] : 0.0f;
#pragma unroll
            for (int r = 0; r < 4; r++) {
                int row = row_base + r;
                float v = acc[m][n][r] + bsum;
                if constexpr (EPI == 2) ((float*)Cout)[(size_t)row * N + col] = v;
                else ((__bf16*)Cout)[(size_t)row * N + col] = f2b(v);
            }
        }
    }
}

// ---------------- fused QKV+C GEMM: A[4096][1024] @ BtAll[4096][1024]^T ----------------
__global__ __launch_bounds__(256) void k_qkvc(
    const __bf16* __restrict__ A, const __bf16* __restrict__ BtAll,
    const float* __restrict__ bq, const float* __restrict__ bk, const float* __restrict__ bv,
    const float* __restrict__ gt2,
    __bf16* __restrict__ mq, __bf16* __restrict__ mk_, __bf16* __restrict__ mv_,
    __bf16* __restrict__ cb)
{
    constexpr int K = 1024;
    __shared__ __bf16 Al[128 * 32];
    __shared__ __bf16 Bl[128 * 32];
    const int bm = blockIdx.x, bn = blockIdx.y;
    const int tid = threadIdx.x, lane = tid & 63, wid = tid >> 6;
    const int l15 = lane & 15, lg = lane >> 4;
    const int qr = (wid >> 1) * 64, qc = (wid & 1) * 64;
    f32x4 acc[4][4] = {};

    const __bf16* Ab = A + (size_t)bm * 128 * K;
    const __bf16* Bb = BtAll + (size_t)bn * 128 * K;

    for (int k0 = 0; k0 < K; k0 += 32) {
#pragma unroll
        for (int c = 0; c < 2; c++) {
            int ch = c * 256 + tid;
            gload_lds16(&Ab[(size_t)(ch >> 2) * K + k0 + (ch & 3) * 8], &Al[ch * 8]);
            gload_lds16(&Bb[(size_t)(ch >> 2) * K + k0 + (ch & 3) * 8], &Bl[ch * 8]);
        }
        __syncthreads();
        bf16x8 af[4], bfv[4];
#pragma unroll
        for (int m = 0; m < 4; m++) af[m] = *(const bf16x8*)&Al[(qr + m * 16 + l15) * 32 + lg * 8];
#pragma unroll
        for (int n = 0; n < 4; n++) bfv[n] = *(const bf16x8*)&Bl[(qc + n * 16 + l15) * 32 + lg * 8];
#pragma unroll
        for (int m = 0; m < 4; m++)
#pragma unroll
            for (int n = 0; n < 4; n++)
                acc[m][n] = __builtin_amdgcn_mfma_f32_16x16x32_bf16(af[m], bfv[n], acc[m][n], 0, 0, 0);
        __syncthreads();
    }
    const int chunk = bn >> 3;
    const float* bias = chunk == 0 ? bq : chunk == 1 ? bk : bv;
    __bf16* outp = chunk == 0 ? mq : chunk == 1 ? mk_ : chunk == 2 ? mv_ : cb;
#pragma unroll
    for (int m = 0; m < 4; m++) {
        int row_base = bm * 128 + qr + m * 16 + lg * 4;
#pragma unroll
        for (int n = 0; n < 4; n++) {
            int col = (bn & 7) * 128 + qc + n * 16 + l15;
#pragma unroll
            for (int r = 0; r < 4; r++) {
                int row = row_base + r;
                float v = acc[m][n][r];
                if (chunk == 3) v = tanhf(v + gt2[(row >> 10) * 1024 + col]);
                else v += bias[col];
                outp[(size_t)row * 1024 + col] = f2b(v);
            }
        }
    }
}

// ---------------- focus-path small kernels (fp32, deterministic 2-stage reductions) ----
__global__ void k_ghs(const float* __restrict__ hs, float* __restrict__ part0) {
    int sc = blockIdx.x, b = blockIdx.y, tid = threadIdx.x;
    int c0 = tid * 4;
    float4 s = {0.f, 0.f, 0.f, 0.f};
    for (int s_ = 0; s_ < 128; s_++) {
        float4 v = *(const float4*)&hs[((size_t)(b * 1024 + sc * 128 + s_)) * 1024 + c0];
        s.x += v.x; s.y += v.y; s.z += v.z; s.w += v.w;
    }
    *(float4*)&part0[(size_t)(sc * 4 + b) * 1024 + c0] = s;
}
__global__ void k_red_ghs(const float* __restrict__ part0, float* __restrict__ ghs) {
    int i = blockIdx.x * 256 + threadIdx.x;
    int b = i >> 10, c = i & 1023;
    float s = 0.f;
    for (int sc = 0; sc < 8; sc++) s += part0[(sc * 4 + b) * 1024 + c];
    ghs[i] = s * (1.0f / 1024.f);
}
__global__ void k_glo2(const float* __restrict__ ghs, const float* __restrict__ wq,
                       float* __restrict__ glo_part) {
    int n = blockIdx.x * 256 + threadIdx.x, kc = blockIdx.y;
    float a0 = 0, a1 = 0, a2 = 0, a3 = 0;
    for (int k = kc * 64; k < kc * 64 + 64; k++) {
        float w = wq[(size_t)k * 1024 + n];
        a0 += ghs[k] * w; a1 += ghs[1024 + k] * w; a2 += ghs[2048 + k] * w; a3 += ghs[3072 + k] * w;
    }
    glo_part[(kc * 4 + 0) * 1024 + n] = a0;
    glo_part[(kc * 4 + 1) * 1024 + n] = a1;
    glo_part[(kc * 4 + 2) * 1024 + n] = a2;
    glo_part[(kc * 4 + 3) * 1024 + n] = a3;
}
__global__ void k_red_glo(const float* __restrict__ glo_part, const float* __restrict__ bq,
                          float* __restrict__ glo) {
    int i = blockIdx.x * 256 + threadIdx.x;
    int b = i >> 10, n = i & 1023;
    float s = bq[n];
    for (int kc = 0; kc < 16; kc++) s += glo_part[(kc * 4 + b) * 1024 + n];
    glo[i] = s;
}
__global__ void k_gt2p(const float* __restrict__ glo, const float* __restrict__ bq,
                       const float* __restrict__ wfg, const float* __restrict__ wfq,
                       float* __restrict__ gt_part) {
    int n = blockIdx.x * 256 + threadIdx.x, kc = blockIdx.y;
    float a0 = 0, a1 = 0, a2 = 0, a3 = 0, t = 0;
    for (int k = kc * 64; k < kc * 64 + 64; k++) {
        float wg = wfg[(size_t)k * 1024 + n];
        float wf = wfq[(size_t)k * 1024 + n];
        a0 += glo[k] * wg; a1 += glo[1024 + k] * wg; a2 += glo[2048 + k] * wg; a3 += glo[3072 + k] * wg;
        t += bq[k] * wf;
    }
    gt_part[(kc * 4 + 0) * 1024 + n] = a0 + t;
    gt_part[(kc * 4 + 1) * 1024 + n] = a1 + t;
    gt_part[(kc * 4 + 2) * 1024 + n] = a2 + t;
    gt_part[(kc * 4 + 3) * 1024 + n] = a3 + t;
}
__global__ void k_red_gt(const float* __restrict__ gt_part, const float* __restrict__ bfg,
                         const float* __restrict__ bfq, float* __restrict__ gt2) {
    int i = blockIdx.x * 256 + threadIdx.x;
    int b = i >> 10, n = i & 1023;
    float s = bfg[n] + bfq[n];
    for (int kc = 0; kc < 16; kc++) s += gt_part[(kc * 4 + b) * 1024 + n];
    gt2[i] = s;
}

// ---------------- P,Z from c ----------------
__global__ void k_pz(const __bf16* __restrict__ cb, const float* __restrict__ up,
                     const float* __restrict__ uz, float* __restrict__ Pf, float* __restrict__ Zf) {
    int i = blockIdx.x * 256 + threadIdx.x;
    int b = i >> 14, h = (i >> 10) & 15, s = i & 1023;
    const __bf16* cp = cb + ((size_t)(b * 1024 + s)) * 1024 + h * 64;
    float p = 0.f, z = 0.f;
#pragma unroll
    for (int c = 0; c < 8; c++) {
        bf16x8 v = *(const bf16x8*)&cp[c * 8];
#pragma unroll
        for (int j = 0; j < 8; j++) {
            float cv = b2f(v[j]);
            p += cv * up[h * 64 + c * 8 + j];
            z += cv * uz[h * 64 + c * 8 + j];
        }
    }
    Pf[i] = 1024.f / (1.f + __expf(-p));
    Zf[i] = 1024.f / (1.f + __expf(-z));
}

// ---------------- V pre-transpose: vt[(b*16+h)*64 + d][s] = mv[b,s,h*64+d] ----------------
__global__ __launch_bounds__(256) void k_vt(const __bf16* __restrict__ mv_, __bf16* __restrict__ vt) {
    __shared__ __bf16 tl[64][72];
    int sc = blockIdx.x, h = blockIdx.y, b = blockIdx.z;
    int tid = threadIdx.x;
#pragma unroll
    for (int i = 0; i < 2; i++) {
        int ch = i * 256 + tid, srow = ch >> 3, off = ch & 7;
        bf16x8 v = *(const bf16x8*)&mv_[((size_t)(b * 1024 + sc * 64 + srow)) * 1024 + h * 64 + off * 8];
        *(bf16x8*)&tl[srow][off * 8] = v;
    }
    __syncthreads();
#pragma unroll
    for (int i = 0; i < 2; i++) {
        int ch = i * 256 + tid, d = ch >> 3, offs = ch & 7;
        bf16x8 o;
#pragma unroll
        for (int j = 0; j < 8; j++) o[j] = tl[offs * 8 + j][d];
        *(bf16x8*)&vt[((size_t)((b * 16 + h) * 64 + d)) * 1024 + sc * 64 + offs * 8] = o;
    }
}

// ---------------- flash attention, swapped-QK^T structure ----------------
DEV bf16x8 ldfrag(const __bf16* base, int row, int colbyte) {
    const char* p = (const char*)base + (size_t)row * 128 + (colbyte ^ ((row & 7) << 4));
    return *(const bf16x8*)p;
}

__global__ __launch_bounds__(256) void k_attn(
    const __bf16* __restrict__ Q, const __bf16* __restrict__ Kx, const __bf16* __restrict__ Vt_g,
    const float* __restrict__ Pf, const float* __restrict__ Zf, __bf16* __restrict__ ctx)
{
    __shared__ __bf16 Kl[2][64 * 64];
    __shared__ __bf16 Vl[2][64 * 64];
    const int qt = blockIdx.x, h = blockIdx.y, b = blockIdx.z;
    const int tid = threadIdx.x, lane = tid & 63, wid = tid >> 6;
    const int l15 = lane & 15, lg = lane >> 4;
    const int qbase = qt * 128 + wid * 32;
    const size_t qoff = ((size_t)(b * Sc)) * DMc + h * Dh;

    // Q fragments: qf[qh][dh] = Q[qbase+qh*16+l15][dh*32 + lg*8 ..]
    bf16x8 qf[2][2];
#pragma unroll
    for (int qh = 0; qh < 2; qh++)
#pragma unroll
        for (int dh = 0; dh < 2; dh++)
            qf[qh][dh] = *(const bf16x8*)&Q[qoff + (size_t)(qbase + qh * 16 + l15) * DMc + dh * 32 + lg * 8];

    float Pr[2], Ar[2];
#pragma unroll
    for (int qh = 0; qh < 2; qh++) {
        int row = qbase + qh * 16 + l15;
        float pp = Pf[((size_t)(b * 16 + h)) * 1024 + row];
        float zz = Zf[((size_t)(b * 16 + h)) * 1024 + row];
        Pr[qh] = pp; Ar[qh] = 2.0f / (zz * zz);
    }
    float m[2] = {-1e30f, -1e30f}, l[2] = {0.f, 0.f};
    f32x4 oacc[2][4] = {};

    const __bf16* Kbase = Kx + qoff;                            // rows s, stride 1024
    const __bf16* Vbase = Vt_g + ((size_t)((b * 16 + h) * 64)) * 1024; // rows d, stride 1024

    // prologue: stage tile 0 into buf 0
#pragma unroll
    for (int i = 0; i < 2; i++) {
        int ch = i * 256 + tid, row = ch >> 3, off = ch & 7;
        uint4v kv = *(const uint4v*)&Kbase[(size_t)row * DMc + off * 8];
        uint4v vv = *(const uint4v*)&Vbase[(size_t)row * 1024 + off * 8];
        *(uint4v*)((char*)&Kl[0][0] + row * 128 + ((off * 16) ^ ((row & 7) << 4))) = kv;
        *(uint4v*)((char*)&Vl[0][0] + row * 128 + ((off * 16) ^ ((row & 7) << 4))) = vv;
    }
    __syncthreads();

    for (int t = 0; t < 16; t++) {
        const int buf = t & 1;
        // T14: issue next-tile global loads now, write to LDS after compute
        uint4v rk[2], rv[2];
        if (t < 15) {
#pragma unroll
            for (int i = 0; i < 2; i++) {
                int ch = i * 256 + tid, row = ch >> 3, off = ch & 7;
                rk[i] = *(const uint4v*)&Kbase[(size_t)((t + 1) * 64 + row) * DMc + off * 8];
                rv[i] = *(const uint4v*)&Vbase[(size_t)row * 1024 + (t + 1) * 64 + off * 8];
            }
        }

        // QK^T swapped: st[qh][c] = S^T fragment (rows k, cols q)
        f32x4 st[2][4];
        __builtin_amdgcn_s_setprio(1);
#pragma unroll
        for (int c = 0; c < 4; c++) {
            bf16x8 kb0 = ldfrag(&Kl[buf][0], c * 16 + l15, lg * 16);
            bf16x8 kb1 = ldfrag(&Kl[buf][0], c * 16 + l15, 64 + lg * 16);
#pragma unroll
            for (int qh = 0; qh < 2; qh++) {
                f32x4 a = {0.f, 0.f, 0.f, 0.f};
                a = __builtin_amdgcn_mfma_f32_16x16x32_bf16(kb0, qf[qh][0], a, 0, 0, 0);
                a = __builtin_amdgcn_mfma_f32_16x16x32_bf16(kb1, qf[qh][1], a, 0, 0, 0);
                st[qh][c] = a;
            }
        }
        __builtin_amdgcn_s_setprio(0);

        // online softmax (per lane: q = qh*16+l15 column; k over (c, lg, r))
        int pk[2][4][2];
#pragma unroll
        for (int qh = 0; qh < 2; qh++) {
            float s[16];
            float mx = -1e30f;
#pragma unroll
            for (int c = 0; c < 4; c++)
#pragma unroll
                for (int r = 0; r < 4; r++) {
                    float kidx = (float)(t * 64 + c * 16 + lg * 4 + r);
                    float dk = kidx - Pr[qh];
                    float v = st[qh][c][r] * 0.125f - dk * dk * Ar[qh];
                    s[c * 4 + r] = v;
                    mx = fmaxf(mx, v);
                }
            mx = fmaxf(mx, __shfl_xor(mx, 16, 64));
            mx = fmaxf(mx, __shfl_xor(mx, 32, 64));
            float nm = fmaxf(m[qh], mx);
            float sc_ = __expf(m[qh] - nm);
            m[qh] = nm;
            float rs = 0.f;
#pragma unroll
            for (int i = 0; i < 16; i++) { float p = __expf(s[i] - nm); s[i] = p; rs += p; }
            rs += __shfl_xor(rs, 16, 64);
            rs += __shfl_xor(rs, 32, 64);
            l[qh] = l[qh] * sc_ + rs;
#pragma unroll
            for (int c = 0; c < 4; c++) {
                pk[qh][c][0] = (int)cvt_pk_bf16(s[c * 4 + 0], s[c * 4 + 1]);
                pk[qh][c][1] = (int)cvt_pk_bf16(s[c * 4 + 2], s[c * 4 + 3]);
            }
#pragma unroll
            for (int r = 0; r < 4; r++) {
                float scr = __shfl(sc_, lg * 4 + r, 16);
#pragma unroll
                for (int dt = 0; dt < 4; dt++) oacc[qh][dt][r] *= scr;
            }
        }

        // PV: exchange P via bpermute, then mfma with Vt fragments
        const int a0 = (((lg & 1) << 1) * 16 + l15) * 4;
        const int a1 = a0 + 64;
        const int selhi = lg >> 1;
#pragma unroll
        for (int kh = 0; kh < 2; kh++) {
            bf16x8 vb[4];
#pragma unroll
            for (int dt = 0; dt < 4; dt++) vb[dt] = ldfrag(&Vl[buf][0], dt * 16 + l15, kh * 64 + lg * 16);
#pragma unroll
            for (int qh = 0; qh < 2; qh++) {
                int w[4];
#pragma unroll
                for (int wi = 0; wi < 4; wi++) {
                    int addr = (wi < 2) ? a0 : a1;
                    int pr = wi & 1;
                    int va = __builtin_amdgcn_ds_bpermute(addr, pk[qh][kh * 2 + 0][pr]);
                    int vb2 = __builtin_amdgcn_ds_bpermute(addr, pk[qh][kh * 2 + 1][pr]);
                    w[wi] = selhi ? vb2 : va;
                }
                i32x4 wv = {w[0], w[1], w[2], w[3]};
                bf16x8 pa = __builtin_bit_cast(bf16x8, wv);
                __builtin_amdgcn_s_setprio(1);
#pragma unroll
                for (int dt = 0; dt < 4; dt++)
                    oacc[qh][dt] = __builtin_amdgcn_mfma_f32_16x16x32_bf16(pa, vb[dt], oacc[qh][dt], 0, 0, 0);
                __builtin_amdgcn_s_setprio(0);
            }
        }

        if (t < 15) {
#pragma unroll
            for (int i = 0; i < 2; i++) {
                int ch = i * 256 + tid, row = ch >> 3, off = ch & 7;
                *(uint4v*)((char*)&Kl[buf ^ 1][0] + row * 128 + ((off * 16) ^ ((row & 7) << 4))) = rk[i];
                *(uint4v*)((char*)&Vl[buf ^ 1][0] + row * 128 + ((off * 16) ^ ((row & 7) << 4))) = rv[i];
            }
        }
        __syncthreads();
    }

    // epilogue
#pragma unroll
    for (int qh = 0; qh < 2; qh++) {
        float lr[4];
#pragma unroll
        for (int r = 0; r < 4; r++) lr[r] = __shfl(l[qh], lg * 4 + r, 16);
#pragma unroll
        for (int dt = 0; dt < 4; dt++)
#pragma unroll
            for (int r = 0; r < 4; r++) {
                int row = qbase + qh * 16 + lg * 4 + r;
                ctx[((size_t)(b * Sc) + row) * DMc + h * Dh + dt * 16 + l15] =
                    f2b(oacc[qh][dt][r] / lr[r]);
            }
    }
}

extern "C" void kernel_launch(void* const* d_in, const int* in_sizes, int n_in,
                              void* d_out, int out_size, void* d_ws, size_t ws_size,
                              hipStream_t stream) {
    const float* hs  = (const float*)d_in[0];
    const float* wq  = (const float*)d_in[1];
    const float* bq  = (const float*)d_in[2];
    const float* wk  = (const float*)d_in[3];
    const float* bk  = (const float*)d_in[4];
    const float* wv  = (const float*)d_in[5];
    const float* bv  = (const float*)d_in[6];
    const float* wo  = (const float*)d_in[7];
    const float* bo  = (const float*)d_in[8];
    const float* wfq = (const float*)d_in[9];
    const float* bfq = (const float*)d_in[10];
    const float* wfg = (const float*)d_in[11];
    const float* bfg = (const float*)d_in[12];
    const float* up  = (const float*)d_in[13];
    const float* uz  = (const float*)d_in[14];

    char* ws = (char*)d_ws;
    const size_t MB = 1ull << 20;
    __bf16* hsb   = (__bf16*)(ws);            // 8MB   (reused by ctxb after qkvc)
    __bf16* BtAll = (__bf16*)(ws + 8 * MB);   // 8MB: [wqT|wkT|wvT|wqfT] as [4096][1024]
    __bf16* wfqT  = (__bf16*)(ws + 16 * MB);  // 2MB
    __bf16* woT   = (__bf16*)(ws + 18 * MB);  // 2MB
    __bf16* mq    = (__bf16*)(ws + 20 * MB);
    __bf16* mk    = (__bf16*)(ws + 28 * MB);
    __bf16* mv    = (__bf16*)(ws + 36 * MB);
    __bf16* cb    = (__bf16*)(ws + 44 * MB);  // reused by vt after k_pz
    __bf16* vt    = (__bf16*)(ws + 44 * MB);
    __bf16* ctxb  = (__bf16*)(ws);
    __bf16* wqb   = (__bf16*)(ws + 55 * MB);  // 2MB: wq row-major bf16 (for wqf GEMM)
    char* sm = ws + 52 * MB;
    float* Pf       = (float*)(sm);
    float* Zf       = (float*)(sm + (256 << 10));
    float* ghs      = (float*)(sm + (512 << 10));
    float* glo      = (float*)(sm + (528 << 10));
    float* gt2      = (float*)(sm + (544 << 10));
    float* part0    = (float*)(sm + (560 << 10));
    float* glo_part = (float*)(sm + (688 << 10));
    float* gt_part  = (float*)(sm + (944 << 10));

    dim3 tb(32, 8);
    k_cvt<<<4096, 256, 0, stream>>>(hs, hsb, Mc * DMc);
    k_cvt<<<1024, 256, 0, stream>>>(wq, wqb, DMc * DMc);
    k_tcvt<<<dim3(32, 32), tb, 0, stream>>>(wq,  BtAll,               DMc, DMc);
    k_tcvt<<<dim3(32, 32), tb, 0, stream>>>(wk,  BtAll + 1048576,     DMc, DMc);
    k_tcvt<<<dim3(32, 32), tb, 0, stream>>>(wv,  BtAll + 2097152,     DMc, DMc);
    k_tcvt<<<dim3(32, 32), tb, 0, stream>>>(wfq, wfqT,                DMc, DMc);
    k_tcvt<<<dim3(32, 32), tb, 0, stream>>>(wo,  woT,                 DMc, DMc);

    // focus-path scalars in fp32 (glo computed from hs directly: mean is linear)
    k_ghs<<<dim3(8, 4), 256, 0, stream>>>(hs, part0);
    k_red_ghs<<<16, 256, 0, stream>>>(part0, ghs);
    k_glo2<<<dim3(4, 16), 256, 0, stream>>>(ghs, wq, glo_part);
    k_red_glo<<<16, 256, 0, stream>>>(glo_part, bq, glo);
    k_gt2p<<<dim3(4, 16), 256, 0, stream>>>(glo, bq, wfg, wfq, gt_part);
    k_red_gt<<<16, 256, 0, stream>>>(gt_part, bfg, bfq, gt2);

    // BtAll slice 3 <- wqf^T where wqf = wq@wfq:
    //   X[n][j] = sum_k wfqT[n][k] * wq[j][k]  => A = wfqT, Bt = wq (row-major bf16)
    k_gemm<0, 64><<<dim3(16, 8), 256, 0, stream>>>(wfqT, wqb, nullptr, BtAll + 3145728, DMc, DMc);

    // fused QKV + focus-c GEMM
    k_qkvc<<<dim3(32, 32), 256, 0, stream>>>(hsb, BtAll, bq, bk, bv, gt2, mq, mk, mv, cb);

    k_pz<<<256, 256, 0, stream>>>(cb, up, uz, Pf, Zf);
    k_vt<<<dim3(16, 16, 4), 256, 0, stream>>>(mv, vt);

    k_attn<<<dim3(8, 16, 4), 256, 0, stream>>>(mq, mk, vt, Pf, Zf, ctxb);

    k_gemm<2, 64><<<dim3(64, 8), 256, 0, stream>>>(ctxb, woT, bo, d_out, DMc, DMc);
}